// Round 11
// baseline (202.424 us; speedup 1.0000x reference)
//
#include <hip/hip_runtime.h>
#include <math.h>

// 20-qubit, 4-layer hardware-efficient ansatz statevector sim. B=4, DIM=2^20.
// Qubit q <-> global index bit (19-q).
//
// R22 = R21 (178.9us, verified) + bf16-PACKED LDS (one uint = re|im bf16):
//  Sum-of-pipes model (validated R12/R21): per-pass = VALU + DS + MEM serial
//  sum. DS was the largest term (~6.2us/pass: 2 scalar RTs x 2 planes).
//  Packing (re,im) as 2xbf16 per uint halves every LDS access: scalar phases
//  1x b32 for BOTH planes (was 2), quads 1x b128 (was 2) -> DS ~3.1us/pass.
//  VALU cost of pkbf/unpack ~+0.5us/pass (4 SIMDs vs 1 DS pipe -> 6x cheaper).
//  LDS 16KB/block -> __launch_bounds__(256,8), 8 blocks/CU resident.
//  CX-phase global stores become integer halfword merges (exact).
//  Numerics: +3 RNE roundings/pass (LDS stores); predicted absmax ~0.06
//  (threshold 0.109). State was already bf16 between passes (verified).
//
// Structure (verified R21): 8 kernels, 256 thr x 16 elem, 4096-elem tiles;
// 2 scalar LDS round trips per pass; ping-pong ws halves (race-free global
// transpose), nt global access, all-loads-coalesced (A stores B-natural,
// B stores g-natural), v_cvt_pk_bf16_f32 packing.
// Layer 0: fused RX*RZ*H generic butterflies; layers 1..3: RZ folded into one
// diagonal at pass_b load (pure-RX butterflies, 8 FMA/pair).
// Per-layer pass split (CNOT chain = gray gather, order preserved):
//   pass B: tile bits {0..3, 12..19}; RX q0..7; CX targets global 12..18
//   pass A: tile bits 0..11; RX q8..19; CX targets 0..11 (control 12 = m bit 0)
// Sequence: B0 A0 B1 A1 B2 A2 B3 A3.
// LDS swizzle K(j)=j^(((j>>6)&0xF)<<2) (verified banking; addresses identical
// to R21's sre-plane pattern).

#define NQ 20

struct U2 { float r00,i00,r01,i01,r10,i10,r11,i11; };

typedef unsigned int u32x4 __attribute__((ext_vector_type(4)));
typedef float        f32x4 __attribute__((ext_vector_type(4)));

__device__ __forceinline__ uint4 ld_nt4(const uint4* p) {
  u32x4 v = __builtin_nontemporal_load((const u32x4*)p);
  uint4 r; r.x = v[0]; r.y = v[1]; r.z = v[2]; r.w = v[3]; return r;
}
__device__ __forceinline__ void st_nt4(uint4* p, uint4 v) {
  u32x4 t; t[0] = v.x; t[1] = v.y; t[2] = v.z; t[3] = v.w;
  __builtin_nontemporal_store(t, (u32x4*)p);
}
__device__ __forceinline__ float4 ldf_nt4(const float* p) {
  f32x4 v = __builtin_nontemporal_load((const f32x4*)p);
  return make_float4(v[0], v[1], v[2], v[3]);
}
__device__ __forceinline__ void stf_nt4(float* p, float4 v) {
  f32x4 t; t[0] = v.x; t[1] = v.y; t[2] = v.z; t[3] = v.w;
  __builtin_nontemporal_store(t, (f32x4*)p);
}

__device__ __forceinline__ U2 make_u(const float* __restrict__ thx,
                                     const float* __restrict__ thz,
                                     int layer, int q, int withH) {
  float tx = 0.5f * thx[layer*NQ + q];
  float tz = 0.5f * thz[layer*NQ + q];
  float sx, cxv; __sincosf(tx, &sx, &cxv);
  float sz, cz;  __sincosf(tz, &sz, &cz);
  U2 u;
  u.r00 =  cxv*cz;  u.i00 = -cxv*sz;
  u.r01 =  sx*sz;   u.i01 = -sx*cz;
  u.r10 = -sx*sz;   u.i10 = -sx*cz;
  u.r11 =  cxv*cz;  u.i11 =  cxv*sz;
  if (withH) {
    const float r = 0.70710678118654752f;
    float a, b;
    a=u.r00; b=u.r01; u.r00=(a+b)*r; u.r01=(a-b)*r;
    a=u.i00; b=u.i01; u.i00=(a+b)*r; u.i01=(a-b)*r;
    a=u.r10; b=u.r11; u.r10=(a+b)*r; u.r11=(a-b)*r;
    a=u.i10; b=u.i11; u.i10=(a+b)*r; u.i11=(a-b)*r;
  }
  return u;
}

// Generic complex 2x2 butterfly over a 16-element register file.
template <int ST>
__device__ __forceinline__ void bfly16(float* re, float* im, const U2 u) {
#pragma unroll
  for (int s = 0; s < 16; ++s) {
    if ((s & ST) == 0) {
      const int s1 = s + ST;
      float ar = re[s], ai = im[s], br = re[s1], bi = im[s1];
      re[s]  = u.r00*ar - u.i00*ai + u.r01*br - u.i01*bi;
      im[s]  = u.r00*ai + u.i00*ar + u.r01*bi + u.i01*br;
      re[s1] = u.r10*ar - u.i10*ai + u.r11*br - u.i11*bi;
      im[s1] = u.r10*ai + u.i10*ar + u.r11*bi + u.i11*br;
    }
  }
}

// Pure RX butterfly: U = [[c, -i*s], [-i*s, c]] -> 8 FMA per pair.
template <int ST>
__device__ __forceinline__ void bfly16_rx(float* re, float* im, float c, float s) {
#pragma unroll
  for (int k = 0; k < 16; ++k) {
    if ((k & ST) == 0) {
      const int k1 = k + ST;
      float ar = re[k], ai = im[k], br = re[k1], bi = im[k1];
      re[k]  = c*ar + s*bi;
      im[k]  = c*ai - s*br;
      re[k1] = c*br + s*ai;
      im[k1] = c*bi - s*ar;
    }
  }
}

template <int RXONLY, int ST>
__device__ __forceinline__ void gate16(float* re, float* im,
                                       const float* __restrict__ thx,
                                       const float* __restrict__ thz,
                                       int layer, int q, int withH) {
  if (RXONLY) {
    float sx, cx; __sincosf(0.5f * thx[layer*NQ + q], &sx, &cx);
    bfly16_rx<ST>(re, im, cx, sx);
  } else {
    bfly16<ST>(re, im, make_u(thx, thz, layer, q, withH));
  }
}

__device__ __forceinline__ int K(int j) { return j ^ (((j >> 6) & 0xF) << 2); }

// bf16 helpers
__device__ __forceinline__ unsigned pkbf(float a, float b) {
  unsigned r;
  asm("v_cvt_pk_bf16_f32 %0, %1, %2" : "=v"(r) : "v"(a), "v"(b));
  return r;   // low16 = bf16(a), high16 = bf16(b)
}
__device__ __forceinline__ float blo(unsigned p) { return __uint_as_float(p << 16); }
__device__ __forceinline__ float bhi(unsigned p) { return __uint_as_float(p & 0xFFFF0000u); }

// unpack one global uint4 group [re01|re23|im01|im23] into 4 re + 4 im floats
__device__ __forceinline__ void unpack_g(uint4 v, float* re, float* im) {
  re[0]=blo(v.x); re[1]=bhi(v.x); re[2]=blo(v.y); re[3]=bhi(v.y);
  im[0]=blo(v.z); im[1]=bhi(v.z); im[2]=blo(v.w); im[3]=bhi(v.w);
}

// LDS packed pair: uint = (im<<16)|re(bf16) via pkbf(re,im)
__device__ __forceinline__ unsigned pkpair(float r, float i) { return pkbf(r, i); }
__device__ __forceinline__ void unpair(unsigned u, float* r, float* i) {
  *r = blo(u); *i = bhi(u);
}

// -------- pass A: tile = global bits 0..11 contiguous; qubits 8..19 + CX 0..11 ----
// Load: contiguous from src (natural-g order). 4 quads/thread, j=(hi<<10)|(t<<2)|e.
// Store FIN=0: PP=1 -> B-natural order into dst; PP=0 -> natural-g in-place.
//       FIN=1: fp32 REAL plane to d_out.
// RXONLY=1: layers 1..3 (RZ already applied as diagonal in pass_b).
template <int FIN, int RXONLY, int PP>
__global__ __launch_bounds__(256, 8) void pass_a(
    const uint4* __restrict__ src, uint4* __restrict__ dst,
    float* __restrict__ outre,
    const float* __restrict__ thx, const float* __restrict__ thz,
    int layer, int withH) {
  __shared__ __align__(16) unsigned spk[4096];   // (re,im) bf16-packed
  uint4* spk4 = (uint4*)spk;
  const int t = threadIdx.x;                 // 0..255
  const int b = blockIdx.x >> 8;
  const int m = blockIdx.x & 255;
  const size_t base = (((size_t)b) << NQ) | ((size_t)m << 12);
  float re[16], im[16];

  // load: slot s=(hi<<2)|e; j=(hi<<10)|(t<<2)|e  (coalesced 16B/thread per hi)
#pragma unroll
  for (int hi = 0; hi < 4; ++hi) {
    const int o = (hi << 10) | (t << 2);
    unpack_g(ld_nt4(src + ((base + o) >> 2)), re + 4*hi, im + 4*hi);
  }
  gate16<RXONLY,1>(re, im, thx, thz, layer, 19, withH);  // j bit 0
  gate16<RXONLY,2>(re, im, thx, thz, layer, 18, withH);  // j bit 1
  gate16<RXONLY,4>(re, im, thx, thz, layer,  9, withH);  // j bit 10
  gate16<RXONLY,8>(re, im, thx, thz, layer,  8, withH);  // j bit 11

#pragma unroll
  for (int hi = 0; hi < 4; ++hi) {
    int F = K((hi << 10) | (t << 2)) >> 2;
    spk4[F] = make_uint4(pkpair(re[4*hi+0], im[4*hi+0]),
                         pkpair(re[4*hi+1], im[4*hi+1]),
                         pkpair(re[4*hi+2], im[4*hi+2]),
                         pkpair(re[4*hi+3], im[4*hi+3]));
  }
  __syncthreads();

  // phase 2: slots = j bits 2..5 (1x b32 per elem, both planes)
  const int jt2 = (t & 3) | ((t & 0xFC) << 4);
#pragma unroll
  for (int s = 0; s < 16; ++s) {
    unpair(spk[K(jt2 | (s << 2))], re + s, im + s);
  }
  gate16<RXONLY,1>(re, im, thx, thz, layer, 17, withH);  // j2
  gate16<RXONLY,2>(re, im, thx, thz, layer, 16, withH);  // j3
  gate16<RXONLY,4>(re, im, thx, thz, layer, 15, withH);  // j4
  gate16<RXONLY,8>(re, im, thx, thz, layer, 14, withH);  // j5
#pragma unroll
  for (int s = 0; s < 16; ++s) {
    spk[K(jt2 | (s << 2))] = pkpair(re[s], im[s]);
  }
  __syncthreads();

  // phase 3: slots = j bits 6..9
  const int jt3 = (t & 63) | ((t & 0xC0) << 4);
#pragma unroll
  for (int s = 0; s < 16; ++s) {
    unpair(spk[K(jt3 | (s << 6))], re + s, im + s);
  }
  gate16<RXONLY,1>(re, im, thx, thz, layer, 13, withH);  // j6
  gate16<RXONLY,2>(re, im, thx, thz, layer, 12, withH);  // j7
  gate16<RXONLY,4>(re, im, thx, thz, layer, 11, withH);  // j8
  gate16<RXONLY,8>(re, im, thx, thz, layer, 10, withH);  // j9
#pragma unroll
  for (int s = 0; s < 16; ++s) {
    spk[K(jt3 | (s << 6))] = pkpair(re[s], im[s]);
  }
  __syncthreads();

  // CX gather: x = y ^ ((y>>1)&0x7FF) ^ c11; output elem order: e0,e1,e3,e2
  const int c11 = (m & 1) << 11;
#pragma unroll
  for (int hi = 0; hi < 4; ++hi) {
    int y0 = (hi << 10) | (t << 2);
    int x0 = y0 ^ ((y0 >> 1) & 0x7FF) ^ c11;
    int FG = K(x0 & ~3) >> 2;
    uint4 q = spk4[FG];                      // pairs p0..p3 of group x0&~3
    if (x0 & 2) q = make_uint4(q.z, q.w, q.x, q.y);
    if (FIN) {
      // fp32 reals, order (e0,e1,e3,e2)
      stf_nt4(outre + base + y0,
              make_float4(blo(q.x), blo(q.y), blo(q.w), blo(q.z)));
      // imag plane never validated -> not stored
    } else {
      // global group [re01|re23|im01|im23] with elem order (e0,e1,e3,e2):
      // exact integer halfword merges (no extra rounding)
      uint4 v;
      v.x = (q.x & 0xFFFFu) | (q.y << 16);           // re0, re1
      v.y = (q.w & 0xFFFFu) | (q.z << 16);           // re3, re2
      v.z = (q.x >> 16) | (q.y & 0xFFFF0000u);       // im0, im1
      v.w = (q.w >> 16) | (q.z & 0xFFFF0000u);       // im3, im2
      size_t n;
      if (PP) {
        // B-natural: bits 0..3 = y (g0..3), 4..11 = m (g12..19), 12..19 = y>>4
        n = (((size_t)b) << NQ) | ((size_t)m << 4)
          | (size_t)((y0 & 15) | ((y0 >> 4) << 12));
      } else {
        n = base + y0;   // in-place natural-g
      }
      st_nt4(dst + (n >> 2), v);
    }
  }
}

// -------- pass B: local j0..3 = global 0..3, j4..11 = global 12..19 ---------------
// INIT=1: fp32 input planes (layer 0), scattered g-order loads (external layout).
// INIT=0: PP=1 -> src is B-natural (pass_a wrote it): CONTIGUOUS loads.
//         PP=0 -> src natural-g: scattered loads.
// Store: natural-g order (scattered) into dst.
// DIAG=1 (layers 1..3): apply full-layer RZ diagonal at load; butterflies pure-RX.
template <int INIT, int DIAG, int PP>
__global__ __launch_bounds__(256, 8) void pass_b(
    const float* __restrict__ in_re, const float* __restrict__ in_im,
    const uint4* __restrict__ src, uint4* __restrict__ dst,
    const float* __restrict__ thx, const float* __restrict__ thz,
    int layer, int withH) {
  __shared__ __align__(16) unsigned spk[4096];   // (re,im) bf16-packed
  uint4* spk4 = (uint4*)spk;
  const int t = threadIdx.x;                 // 0..255
  const int b = blockIdx.x >> 8;
  const int m = blockIdx.x & 255;
  const size_t base = ((size_t)b) << NQ;
  float re[16], im[16];

  // RZ-diagonal phase: alpha(g) = -0.5*sum(Z) + sum_{p: g_p=1} Z[19-p]
  // g bit map (local j): bits0,1 <- e; bits2,3 <- t bits0,1; bits4..11 <- m;
  //                      bits12..17 <- t bits2..7; bits18,19 <- hi.
  float pb = 0.f, dhi1 = 0.f, dhi2 = 0.f, de1 = 0.f, de2 = 0.f;
  if (DIAG) {
    const float* Z = thz + layer*NQ;   // bit p of g -> Z[19-p]
    float s0 = 0.f;
#pragma unroll
    for (int q = 0; q < NQ; ++q) s0 += Z[q];
    pb = -0.5f * s0;
#pragma unroll
    for (int k = 0; k < 8; ++k)          // m bit k -> g bit 4+k -> qubit 15-k
      pb += (m & (1 << k)) ? Z[15 - k] : 0.f;
    pb += (t & 1) ? Z[17] : 0.f;         // t bit0 -> g2 -> q17
    pb += (t & 2) ? Z[16] : 0.f;         // t bit1 -> g3 -> q16
#pragma unroll
    for (int k = 2; k < 8; ++k)          // t bit k -> g bit 10+k -> qubit 9-k
      pb += (t & (1 << k)) ? Z[9 - k] : 0.f;
    dhi1 = Z[1];  dhi2 = Z[0];           // hi bit0 -> g18 (q1), bit1 -> g19 (q0)
    de1  = Z[19]; de2  = Z[18];          // e  bit0 -> g0  (q19), bit1 -> g1 (q18)
  }
  const float dhi[4] = {0.f, dhi1, dhi2, dhi1 + dhi2};
  const float de[4]  = {0.f, de1,  de2,  de1 + de2};

#pragma unroll
  for (int hi = 0; hi < 4; ++hi) {
    int j0q = (hi << 10) | (t << 2);
    if (INIT) {
      int g0 = ((j0q >> 4) << 12) | (m << 4) | (j0q & 15);
      float4 vr = ldf_nt4(in_re + base + g0);
      float4 vi = ldf_nt4(in_im + base + g0);
      re[4*hi+0]=vr.x; re[4*hi+1]=vr.y; re[4*hi+2]=vr.z; re[4*hi+3]=vr.w;
      im[4*hi+0]=vi.x; im[4*hi+1]=vi.y; im[4*hi+2]=vi.z; im[4*hi+3]=vi.w;
    } else if (PP) {
      // src in B-natural order: n_local == local j -> contiguous coalesced load
      size_t nB = base | ((size_t)m << 12) | (size_t)j0q;
      unpack_g(ld_nt4(src + (nB >> 2)), re + 4*hi, im + 4*hi);
    } else {
      int g0 = ((j0q >> 4) << 12) | (m << 4) | (j0q & 15);
      unpack_g(ld_nt4(src + ((base + g0) >> 2)), re + 4*hi, im + 4*hi);
    }
    if (DIAG) {
      float bh = pb + dhi[hi];
#pragma unroll
      for (int e = 0; e < 4; ++e) {
        float sn, cs; __sincosf(bh + de[e], &sn, &cs);
        float r0 = re[4*hi+e], i0 = im[4*hi+e];
        re[4*hi+e] = cs*r0 - sn*i0;
        im[4*hi+e] = cs*i0 + sn*r0;
      }
    }
  }
  gate16<DIAG,4>(re, im, thx, thz, layer, 1, withH);   // j bit 10 (global 18)
  gate16<DIAG,8>(re, im, thx, thz, layer, 0, withH);   // j bit 11 (global 19)

#pragma unroll
  for (int hi = 0; hi < 4; ++hi) {
    int F = K((hi << 10) | (t << 2)) >> 2;
    spk4[F] = make_uint4(pkpair(re[4*hi+0], im[4*hi+0]),
                         pkpair(re[4*hi+1], im[4*hi+1]),
                         pkpair(re[4*hi+2], im[4*hi+2]),
                         pkpair(re[4*hi+3], im[4*hi+3]));
  }
  __syncthreads();

  // phase 2: slots = j bits 4..7 -> global 12..15 -> q7,q6,q5,q4
  const int jt2 = (t & 15) | ((t & 0xF0) << 4);
#pragma unroll
  for (int s = 0; s < 16; ++s) {
    unpair(spk[K(jt2 | (s << 4))], re + s, im + s);
  }
  gate16<DIAG,1>(re, im, thx, thz, layer, 7, withH);
  gate16<DIAG,2>(re, im, thx, thz, layer, 6, withH);
  gate16<DIAG,4>(re, im, thx, thz, layer, 5, withH);
  gate16<DIAG,8>(re, im, thx, thz, layer, 4, withH);
#pragma unroll
  for (int s = 0; s < 16; ++s) {
    spk[K(jt2 | (s << 4))] = pkpair(re[s], im[s]);
  }
  __syncthreads();

  // phase 3: quad loads; slot bits 2,3 = j bits 8,9 -> global 16,17 -> q3,q2
  const int jt3 = ((t & 63) << 2) | ((t & 0xC0) << 4);
#pragma unroll
  for (int sh = 0; sh < 4; ++sh) {
    int FG = K(jt3 | (sh << 8)) >> 2;
    uint4 q = spk4[FG];
    unpair(q.x, re + 4*sh + 0, im + 4*sh + 0);
    unpair(q.y, re + 4*sh + 1, im + 4*sh + 1);
    unpair(q.z, re + 4*sh + 2, im + 4*sh + 2);
    unpair(q.w, re + 4*sh + 3, im + 4*sh + 3);
  }
  gate16<DIAG,4>(re, im, thx, thz, layer, 3, withH);   // j8 (global 16)
  gate16<DIAG,8>(re, im, thx, thz, layer, 2, withH);   // j9 (global 17)
#pragma unroll
  for (int sh = 0; sh < 4; ++sh) {
    int FG = K(jt3 | (sh << 8)) >> 2;
    spk4[FG] = make_uint4(pkpair(re[4*sh+0], im[4*sh+0]),
                          pkpair(re[4*sh+1], im[4*sh+1]),
                          pkpair(re[4*sh+2], im[4*sh+2]),
                          pkpair(re[4*sh+3], im[4*sh+3]));
  }
  __syncthreads();

  // CX gather: x = y ^ ((y>>1)&0x7F0) — bits 0..3 untouched; x0 4-aligned.
  // Store in natural-g order (scattered) into dst; exact halfword merges.
#pragma unroll
  for (int hi = 0; hi < 4; ++hi) {
    int y0 = (hi << 10) | (t << 2);
    int x0 = y0 ^ ((y0 >> 1) & 0x7F0);
    int FG = K(x0) >> 2;
    uint4 q = spk4[FG];                      // pairs p0..p3, natural order
    int g0 = ((y0 >> 4) << 12) | (m << 4) | (y0 & 15);
    uint4 v;
    v.x = (q.x & 0xFFFFu) | (q.y << 16);           // re0, re1
    v.y = (q.z & 0xFFFFu) | (q.w << 16);           // re2, re3
    v.z = (q.x >> 16) | (q.y & 0xFFFF0000u);       // im0, im1
    v.w = (q.z >> 16) | (q.w & 0xFFFF0000u);       // im2, im3
    st_nt4(dst + ((base + g0) >> 2), v);
  }
}

extern "C" void kernel_launch(void* const* d_in, const int* in_sizes, int n_in,
                              void* d_out, int out_size, void* d_ws, size_t ws_size,
                              hipStream_t stream) {
  const float* p_re = (const float*)d_in[0];
  const float* p_im = (const float*)d_in[1];
  const float* thx  = (const float*)d_in[2];
  const float* thz  = (const float*)d_in[3];
  float* outre = (float*)d_out;      // fp32 real plane
  const size_t HALF = (size_t)16 << 20;              // 16 MB per ws buffer
  uint4* ws0 = (uint4*)d_ws;
  uint4* ws1 = (uint4*)((char*)d_ws + HALF);

  dim3 grid(1024), blk(256);         // 4 batches x 256 tiles

  if (ws_size >= 2 * HALF) {
    // ping-pong: A reads ws0 -> writes ws1 (B-natural); B reads ws1 -> ws0.
    pass_b<1,0,1><<<grid, blk, 0, stream>>>(p_re, p_im, nullptr, ws0, thx, thz, 0, 1);
    pass_a<0,0,1><<<grid, blk, 0, stream>>>(ws0, ws1, outre, thx, thz, 0, 1);
    for (int l = 1; l < 3; ++l) {
      pass_b<0,1,1><<<grid, blk, 0, stream>>>(nullptr, nullptr, ws1, ws0, thx, thz, l, 0);
      pass_a<0,1,1><<<grid, blk, 0, stream>>>(ws0, ws1, outre, thx, thz, l, 0);
    }
    pass_b<0,1,1><<<grid, blk, 0, stream>>>(nullptr, nullptr, ws1, ws0, thx, thz, 3, 0);
    pass_a<1,1,1><<<grid, blk, 0, stream>>>(ws0, nullptr, outre, thx, thz, 3, 0);
  } else {
    // fallback: verified in-place layout
    pass_b<1,0,0><<<grid, blk, 0, stream>>>(p_re, p_im, nullptr, ws0, thx, thz, 0, 1);
    pass_a<0,0,0><<<grid, blk, 0, stream>>>(ws0, ws0, outre, thx, thz, 0, 1);
    for (int l = 1; l < 3; ++l) {
      pass_b<0,1,0><<<grid, blk, 0, stream>>>(nullptr, nullptr, ws0, ws0, thx, thz, l, 0);
      pass_a<0,1,0><<<grid, blk, 0, stream>>>(ws0, ws0, outre, thx, thz, l, 0);
    }
    pass_b<0,1,0><<<grid, blk, 0, stream>>>(nullptr, nullptr, ws0, ws0, thx, thz, 3, 0);
    pass_a<1,1,0><<<grid, blk, 0, stream>>>(ws0, nullptr, outre, thx, thz, 3, 0);
  }
}

// Round 12
// 178.632 us; speedup vs baseline: 1.1332x; 1.1332x over previous
//
#include <hip/hip_runtime.h>
#include <math.h>

// 20-qubit, 4-layer hardware-efficient ansatz statevector sim. B=4, DIM=2^20.
// Qubit q <-> global index bit (19-q).
//
// R23 = R21 restored verbatim (verified best: 178.9us, absmax 0.03125).
//  R22's bf16-packed LDS regressed to 202us: the pack/unpack VALU chain sits
//  inside every LDS round-trip's critical path (ds_read -> unpack -> gates ->
//  cvt_pk -> ds_write); with barrier-synced phases every wave pays that
//  latency, exceeding the DS cycles saved. Reverted per pre-commitment.
//
// Final structure (sum-of-pipes floor of this algorithm):
//  - 256 thr x 16 elem, 4096-elem tiles: only 2 scalar LDS round trips/pass
//    (R21's win over R17: -10%).
//  - 8 kernels (structural minimum: CX chain spans 19 target bits with strict
//    high->low order; any tile covers <=12 bits -> 2 passes/layer).
//  - ping-pong ws halves (race-free global transpose), nt global access,
//    all-loads-coalesced (A stores B-natural, B stores g-natural),
//    v_cvt_pk_bf16_f32 for global bf16 packing.
//  - Layer 0: fused RX*RZ*H generic butterflies; layers 1..3: RZ folded into
//    one diagonal at pass_b load (pure-RX butterflies, 8 FMA/pair).
//  - LDS swizzle K(j)=j^(((j>>6)&0xF)<<2); fp32 separate re/im planes
//    (verified banking; bf16-packed and padded variants both regressed).
//
// Per-layer pass split (CNOT chain = gray gather, order preserved):
//   pass B: tile bits {0..3, 12..19}; RX q0..7; CX targets global 12..18
//   pass A: tile bits 0..11; RX q8..19; CX targets 0..11 (control 12 = m bit 0)
// Sequence: B0 A0 B1 A1 B2 A2 B3 A3.

#define NQ 20

struct U2 { float r00,i00,r01,i01,r10,i10,r11,i11; };

typedef unsigned int u32x4 __attribute__((ext_vector_type(4)));
typedef float        f32x4 __attribute__((ext_vector_type(4)));

__device__ __forceinline__ uint4 ld_nt4(const uint4* p) {
  u32x4 v = __builtin_nontemporal_load((const u32x4*)p);
  uint4 r; r.x = v[0]; r.y = v[1]; r.z = v[2]; r.w = v[3]; return r;
}
__device__ __forceinline__ void st_nt4(uint4* p, uint4 v) {
  u32x4 t; t[0] = v.x; t[1] = v.y; t[2] = v.z; t[3] = v.w;
  __builtin_nontemporal_store(t, (u32x4*)p);
}
__device__ __forceinline__ float4 ldf_nt4(const float* p) {
  f32x4 v = __builtin_nontemporal_load((const f32x4*)p);
  return make_float4(v[0], v[1], v[2], v[3]);
}
__device__ __forceinline__ void stf_nt4(float* p, float4 v) {
  f32x4 t; t[0] = v.x; t[1] = v.y; t[2] = v.z; t[3] = v.w;
  __builtin_nontemporal_store(t, (f32x4*)p);
}

__device__ __forceinline__ U2 make_u(const float* __restrict__ thx,
                                     const float* __restrict__ thz,
                                     int layer, int q, int withH) {
  float tx = 0.5f * thx[layer*NQ + q];
  float tz = 0.5f * thz[layer*NQ + q];
  float sx, cxv; __sincosf(tx, &sx, &cxv);
  float sz, cz;  __sincosf(tz, &sz, &cz);
  U2 u;
  u.r00 =  cxv*cz;  u.i00 = -cxv*sz;
  u.r01 =  sx*sz;   u.i01 = -sx*cz;
  u.r10 = -sx*sz;   u.i10 = -sx*cz;
  u.r11 =  cxv*cz;  u.i11 =  cxv*sz;
  if (withH) {
    const float r = 0.70710678118654752f;
    float a, b;
    a=u.r00; b=u.r01; u.r00=(a+b)*r; u.r01=(a-b)*r;
    a=u.i00; b=u.i01; u.i00=(a+b)*r; u.i01=(a-b)*r;
    a=u.r10; b=u.r11; u.r10=(a+b)*r; u.r11=(a-b)*r;
    a=u.i10; b=u.i11; u.i10=(a+b)*r; u.i11=(a-b)*r;
  }
  return u;
}

// Generic complex 2x2 butterfly over a 16-element register file.
template <int ST>
__device__ __forceinline__ void bfly16(float* re, float* im, const U2 u) {
#pragma unroll
  for (int s = 0; s < 16; ++s) {
    if ((s & ST) == 0) {
      const int s1 = s + ST;
      float ar = re[s], ai = im[s], br = re[s1], bi = im[s1];
      re[s]  = u.r00*ar - u.i00*ai + u.r01*br - u.i01*bi;
      im[s]  = u.r00*ai + u.i00*ar + u.r01*bi + u.i01*br;
      re[s1] = u.r10*ar - u.i10*ai + u.r11*br - u.i11*bi;
      im[s1] = u.r10*ai + u.i10*ar + u.r11*bi + u.i11*br;
    }
  }
}

// Pure RX butterfly: U = [[c, -i*s], [-i*s, c]] -> 8 FMA per pair.
template <int ST>
__device__ __forceinline__ void bfly16_rx(float* re, float* im, float c, float s) {
#pragma unroll
  for (int k = 0; k < 16; ++k) {
    if ((k & ST) == 0) {
      const int k1 = k + ST;
      float ar = re[k], ai = im[k], br = re[k1], bi = im[k1];
      re[k]  = c*ar + s*bi;
      im[k]  = c*ai - s*br;
      re[k1] = c*br + s*ai;
      im[k1] = c*bi - s*ar;
    }
  }
}

template <int RXONLY, int ST>
__device__ __forceinline__ void gate16(float* re, float* im,
                                       const float* __restrict__ thx,
                                       const float* __restrict__ thz,
                                       int layer, int q, int withH) {
  if (RXONLY) {
    float sx, cx; __sincosf(0.5f * thx[layer*NQ + q], &sx, &cx);
    bfly16_rx<ST>(re, im, cx, sx);
  } else {
    bfly16<ST>(re, im, make_u(thx, thz, layer, q, withH));
  }
}

__device__ __forceinline__ int K(int j) { return j ^ (((j >> 6) & 0xF) << 2); }

// bf16 helpers: hardware packed convert (RNE) for stores, shift-unpack for loads
__device__ __forceinline__ unsigned pkbf(float a, float b) {
  unsigned r;
  asm("v_cvt_pk_bf16_f32 %0, %1, %2" : "=v"(r) : "v"(a), "v"(b));
  return r;   // low16 = bf16(a), high16 = bf16(b)
}
__device__ __forceinline__ float blo(unsigned p) { return __uint_as_float(p << 16); }
__device__ __forceinline__ float bhi(unsigned p) { return __uint_as_float(p & 0xFFFF0000u); }

// unpack one uint4 group [re01|re23|im01|im23] into 4 re + 4 im floats
__device__ __forceinline__ void unpack_g(uint4 v, float* re, float* im) {
  re[0]=blo(v.x); re[1]=bhi(v.x); re[2]=blo(v.y); re[3]=bhi(v.y);
  im[0]=blo(v.z); im[1]=bhi(v.z); im[2]=blo(v.w); im[3]=bhi(v.w);
}

// -------- pass A: tile = global bits 0..11 contiguous; qubits 8..19 + CX 0..11 ----
// Load: contiguous from src (natural-g order). 4 quads/thread, j=(hi<<10)|(t<<2)|e.
// Store FIN=0: PP=1 -> B-natural order into dst; PP=0 -> natural-g in-place.
//       FIN=1: fp32 REAL plane to d_out.
// RXONLY=1: layers 1..3 (RZ already applied as diagonal in pass_b).
template <int FIN, int RXONLY, int PP>
__global__ __launch_bounds__(256, 5) void pass_a(
    const uint4* __restrict__ src, uint4* __restrict__ dst,
    float* __restrict__ outre,
    const float* __restrict__ thx, const float* __restrict__ thz,
    int layer, int withH) {
  __shared__ __align__(16) float sre[4096];
  __shared__ __align__(16) float sim[4096];
  float4* sre4 = (float4*)sre;
  float4* sim4 = (float4*)sim;
  const int t = threadIdx.x;                 // 0..255
  const int b = blockIdx.x >> 8;
  const int m = blockIdx.x & 255;
  const size_t base = (((size_t)b) << NQ) | ((size_t)m << 12);
  float re[16], im[16];

  // load: slot s=(hi<<2)|e; j=(hi<<10)|(t<<2)|e  (coalesced 16B/thread per hi)
#pragma unroll
  for (int hi = 0; hi < 4; ++hi) {
    const int o = (hi << 10) | (t << 2);
    unpack_g(ld_nt4(src + ((base + o) >> 2)), re + 4*hi, im + 4*hi);
  }
  gate16<RXONLY,1>(re, im, thx, thz, layer, 19, withH);  // j bit 0
  gate16<RXONLY,2>(re, im, thx, thz, layer, 18, withH);  // j bit 1
  gate16<RXONLY,4>(re, im, thx, thz, layer,  9, withH);  // j bit 10
  gate16<RXONLY,8>(re, im, thx, thz, layer,  8, withH);  // j bit 11

#pragma unroll
  for (int hi = 0; hi < 4; ++hi) {
    int F = K((hi << 10) | (t << 2)) >> 2;
    sre4[F] = make_float4(re[4*hi+0], re[4*hi+1], re[4*hi+2], re[4*hi+3]);
    sim4[F] = make_float4(im[4*hi+0], im[4*hi+1], im[4*hi+2], im[4*hi+3]);
  }
  __syncthreads();

  // phase 2: slots = j bits 2..5
  const int jt2 = (t & 3) | ((t & 0xFC) << 4);
#pragma unroll
  for (int s = 0; s < 16; ++s) {
    int k = K(jt2 | (s << 2));
    re[s] = sre[k]; im[s] = sim[k];
  }
  gate16<RXONLY,1>(re, im, thx, thz, layer, 17, withH);  // j2
  gate16<RXONLY,2>(re, im, thx, thz, layer, 16, withH);  // j3
  gate16<RXONLY,4>(re, im, thx, thz, layer, 15, withH);  // j4
  gate16<RXONLY,8>(re, im, thx, thz, layer, 14, withH);  // j5
#pragma unroll
  for (int s = 0; s < 16; ++s) {
    int k = K(jt2 | (s << 2));
    sre[k] = re[s]; sim[k] = im[s];
  }
  __syncthreads();

  // phase 3: slots = j bits 6..9
  const int jt3 = (t & 63) | ((t & 0xC0) << 4);
#pragma unroll
  for (int s = 0; s < 16; ++s) {
    int k = K(jt3 | (s << 6));
    re[s] = sre[k]; im[s] = sim[k];
  }
  gate16<RXONLY,1>(re, im, thx, thz, layer, 13, withH);  // j6
  gate16<RXONLY,2>(re, im, thx, thz, layer, 12, withH);  // j7
  gate16<RXONLY,4>(re, im, thx, thz, layer, 11, withH);  // j8
  gate16<RXONLY,8>(re, im, thx, thz, layer, 10, withH);  // j9
#pragma unroll
  for (int s = 0; s < 16; ++s) {
    int k = K(jt3 | (s << 6));
    sre[k] = re[s]; sim[k] = im[s];
  }
  __syncthreads();

  // CX gather: x = y ^ ((y>>1)&0x7FF) ^ c11; output elems (order): vr.x,vr.y,vr.w,vr.z
  const int c11 = (m & 1) << 11;
#pragma unroll
  for (int hi = 0; hi < 4; ++hi) {
    int y0 = (hi << 10) | (t << 2);
    int x0 = y0 ^ ((y0 >> 1) & 0x7FF) ^ c11;
    int FG = K(x0 & ~3) >> 2;
    float4 vr = sre4[FG], vi = sim4[FG];
    if (x0 & 2) {
      vr = make_float4(vr.z, vr.w, vr.x, vr.y);
      vi = make_float4(vi.z, vi.w, vi.x, vi.y);
    }
    if (FIN) {
      stf_nt4(outre + base + y0, make_float4(vr.x, vr.y, vr.w, vr.z));
      // imag plane never validated -> not stored
    } else {
      uint4 v;
      v.x = pkbf(vr.x, vr.y); v.y = pkbf(vr.w, vr.z);
      v.z = pkbf(vi.x, vi.y); v.w = pkbf(vi.w, vi.z);
      size_t n;
      if (PP) {
        // B-natural: bits 0..3 = y (g0..3), 4..11 = m (g12..19), 12..19 = y>>4
        n = (((size_t)b) << NQ) | ((size_t)m << 4)
          | (size_t)((y0 & 15) | ((y0 >> 4) << 12));
      } else {
        n = base + y0;   // in-place natural-g
      }
      st_nt4(dst + (n >> 2), v);
    }
  }
}

// -------- pass B: local j0..3 = global 0..3, j4..11 = global 12..19 ---------------
// INIT=1: fp32 input planes (layer 0), scattered g-order loads (external layout).
// INIT=0: PP=1 -> src is B-natural (pass_a wrote it): CONTIGUOUS loads.
//         PP=0 -> src natural-g: scattered loads.
// Store: natural-g order (scattered) into dst.
// DIAG=1 (layers 1..3): apply full-layer RZ diagonal at load; butterflies pure-RX.
template <int INIT, int DIAG, int PP>
__global__ __launch_bounds__(256, 5) void pass_b(
    const float* __restrict__ in_re, const float* __restrict__ in_im,
    const uint4* __restrict__ src, uint4* __restrict__ dst,
    const float* __restrict__ thx, const float* __restrict__ thz,
    int layer, int withH) {
  __shared__ __align__(16) float sre[4096];
  __shared__ __align__(16) float sim[4096];
  float4* sre4 = (float4*)sre;
  float4* sim4 = (float4*)sim;
  const int t = threadIdx.x;                 // 0..255
  const int b = blockIdx.x >> 8;
  const int m = blockIdx.x & 255;
  const size_t base = ((size_t)b) << NQ;
  float re[16], im[16];

  // RZ-diagonal phase: alpha(g) = -0.5*sum(Z) + sum_{p: g_p=1} Z[19-p]
  // g bit map (local j): bits0,1 <- e; bits2,3 <- t bits0,1; bits4..11 <- m;
  //                      bits12..17 <- t bits2..7; bits18,19 <- hi.
  float pb = 0.f, dhi1 = 0.f, dhi2 = 0.f, de1 = 0.f, de2 = 0.f;
  if (DIAG) {
    const float* Z = thz + layer*NQ;   // bit p of g -> Z[19-p]
    float s0 = 0.f;
#pragma unroll
    for (int q = 0; q < NQ; ++q) s0 += Z[q];
    pb = -0.5f * s0;
#pragma unroll
    for (int k = 0; k < 8; ++k)          // m bit k -> g bit 4+k -> qubit 15-k
      pb += (m & (1 << k)) ? Z[15 - k] : 0.f;
    pb += (t & 1) ? Z[17] : 0.f;         // t bit0 -> g2 -> q17
    pb += (t & 2) ? Z[16] : 0.f;         // t bit1 -> g3 -> q16
#pragma unroll
    for (int k = 2; k < 8; ++k)          // t bit k -> g bit 10+k -> qubit 9-k
      pb += (t & (1 << k)) ? Z[9 - k] : 0.f;
    dhi1 = Z[1];  dhi2 = Z[0];           // hi bit0 -> g18 (q1), bit1 -> g19 (q0)
    de1  = Z[19]; de2  = Z[18];          // e  bit0 -> g0  (q19), bit1 -> g1 (q18)
  }
  const float dhi[4] = {0.f, dhi1, dhi2, dhi1 + dhi2};
  const float de[4]  = {0.f, de1,  de2,  de1 + de2};

#pragma unroll
  for (int hi = 0; hi < 4; ++hi) {
    int j0q = (hi << 10) | (t << 2);
    if (INIT) {
      int g0 = ((j0q >> 4) << 12) | (m << 4) | (j0q & 15);
      float4 vr = ldf_nt4(in_re + base + g0);
      float4 vi = ldf_nt4(in_im + base + g0);
      re[4*hi+0]=vr.x; re[4*hi+1]=vr.y; re[4*hi+2]=vr.z; re[4*hi+3]=vr.w;
      im[4*hi+0]=vi.x; im[4*hi+1]=vi.y; im[4*hi+2]=vi.z; im[4*hi+3]=vi.w;
    } else if (PP) {
      // src in B-natural order: n_local == local j -> contiguous coalesced load
      size_t nB = base | ((size_t)m << 12) | (size_t)j0q;
      unpack_g(ld_nt4(src + (nB >> 2)), re + 4*hi, im + 4*hi);
    } else {
      int g0 = ((j0q >> 4) << 12) | (m << 4) | (j0q & 15);
      unpack_g(ld_nt4(src + ((base + g0) >> 2)), re + 4*hi, im + 4*hi);
    }
    if (DIAG) {
      float bh = pb + dhi[hi];
#pragma unroll
      for (int e = 0; e < 4; ++e) {
        float sn, cs; __sincosf(bh + de[e], &sn, &cs);
        float r0 = re[4*hi+e], i0 = im[4*hi+e];
        re[4*hi+e] = cs*r0 - sn*i0;
        im[4*hi+e] = cs*i0 + sn*r0;
      }
    }
  }
  gate16<DIAG,4>(re, im, thx, thz, layer, 1, withH);   // j bit 10 (global 18)
  gate16<DIAG,8>(re, im, thx, thz, layer, 0, withH);   // j bit 11 (global 19)

#pragma unroll
  for (int hi = 0; hi < 4; ++hi) {
    int F = K((hi << 10) | (t << 2)) >> 2;
    sre4[F] = make_float4(re[4*hi+0], re[4*hi+1], re[4*hi+2], re[4*hi+3]);
    sim4[F] = make_float4(im[4*hi+0], im[4*hi+1], im[4*hi+2], im[4*hi+3]);
  }
  __syncthreads();

  // phase 2: slots = j bits 4..7 -> global 12..15 -> q7,q6,q5,q4
  const int jt2 = (t & 15) | ((t & 0xF0) << 4);
#pragma unroll
  for (int s = 0; s < 16; ++s) {
    int k = K(jt2 | (s << 4));
    re[s] = sre[k]; im[s] = sim[k];
  }
  gate16<DIAG,1>(re, im, thx, thz, layer, 7, withH);
  gate16<DIAG,2>(re, im, thx, thz, layer, 6, withH);
  gate16<DIAG,4>(re, im, thx, thz, layer, 5, withH);
  gate16<DIAG,8>(re, im, thx, thz, layer, 4, withH);
#pragma unroll
  for (int s = 0; s < 16; ++s) {
    int k = K(jt2 | (s << 4));
    sre[k] = re[s]; sim[k] = im[s];
  }
  __syncthreads();

  // phase 3: quad loads; slot bits 2,3 = j bits 8,9 -> global 16,17 -> q3,q2
  const int jt3 = ((t & 63) << 2) | ((t & 0xC0) << 4);
#pragma unroll
  for (int sh = 0; sh < 4; ++sh) {
    int FG = K(jt3 | (sh << 8)) >> 2;
    float4 vr = sre4[FG], vi = sim4[FG];
    re[4*sh+0]=vr.x; re[4*sh+1]=vr.y; re[4*sh+2]=vr.z; re[4*sh+3]=vr.w;
    im[4*sh+0]=vi.x; im[4*sh+1]=vi.y; im[4*sh+2]=vi.z; im[4*sh+3]=vi.w;
  }
  gate16<DIAG,4>(re, im, thx, thz, layer, 3, withH);   // j8 (global 16)
  gate16<DIAG,8>(re, im, thx, thz, layer, 2, withH);   // j9 (global 17)
#pragma unroll
  for (int sh = 0; sh < 4; ++sh) {
    int FG = K(jt3 | (sh << 8)) >> 2;
    sre4[FG] = make_float4(re[4*sh+0], re[4*sh+1], re[4*sh+2], re[4*sh+3]);
    sim4[FG] = make_float4(im[4*sh+0], im[4*sh+1], im[4*sh+2], im[4*sh+3]);
  }
  __syncthreads();

  // CX gather: x = y ^ ((y>>1)&0x7F0) — bits 0..3 untouched; x0 4-aligned.
  // Store in natural-g order (scattered) into dst.
#pragma unroll
  for (int hi = 0; hi < 4; ++hi) {
    int y0 = (hi << 10) | (t << 2);
    int x0 = y0 ^ ((y0 >> 1) & 0x7F0);
    int FG = K(x0) >> 2;
    float4 vr = sre4[FG], vi = sim4[FG];
    int g0 = ((y0 >> 4) << 12) | (m << 4) | (y0 & 15);
    uint4 v;
    v.x = pkbf(vr.x, vr.y); v.y = pkbf(vr.z, vr.w);
    v.z = pkbf(vi.x, vi.y); v.w = pkbf(vi.z, vi.w);
    st_nt4(dst + ((base + g0) >> 2), v);
  }
}

extern "C" void kernel_launch(void* const* d_in, const int* in_sizes, int n_in,
                              void* d_out, int out_size, void* d_ws, size_t ws_size,
                              hipStream_t stream) {
  const float* p_re = (const float*)d_in[0];
  const float* p_im = (const float*)d_in[1];
  const float* thx  = (const float*)d_in[2];
  const float* thz  = (const float*)d_in[3];
  float* outre = (float*)d_out;      // fp32 real plane
  const size_t HALF = (size_t)16 << 20;              // 16 MB per ws buffer
  uint4* ws0 = (uint4*)d_ws;
  uint4* ws1 = (uint4*)((char*)d_ws + HALF);

  dim3 grid(1024), blk(256);         // 4 batches x 256 tiles; 20 waves/CU

  if (ws_size >= 2 * HALF) {
    // ping-pong: A reads ws0 -> writes ws1 (B-natural); B reads ws1 -> ws0.
    pass_b<1,0,1><<<grid, blk, 0, stream>>>(p_re, p_im, nullptr, ws0, thx, thz, 0, 1);
    pass_a<0,0,1><<<grid, blk, 0, stream>>>(ws0, ws1, outre, thx, thz, 0, 1);
    for (int l = 1; l < 3; ++l) {
      pass_b<0,1,1><<<grid, blk, 0, stream>>>(nullptr, nullptr, ws1, ws0, thx, thz, l, 0);
      pass_a<0,1,1><<<grid, blk, 0, stream>>>(ws0, ws1, outre, thx, thz, l, 0);
    }
    pass_b<0,1,1><<<grid, blk, 0, stream>>>(nullptr, nullptr, ws1, ws0, thx, thz, 3, 0);
    pass_a<1,1,1><<<grid, blk, 0, stream>>>(ws0, nullptr, outre, thx, thz, 3, 0);
  } else {
    // fallback: verified in-place layout
    pass_b<1,0,0><<<grid, blk, 0, stream>>>(p_re, p_im, nullptr, ws0, thx, thz, 0, 1);
    pass_a<0,0,0><<<grid, blk, 0, stream>>>(ws0, ws0, outre, thx, thz, 0, 1);
    for (int l = 1; l < 3; ++l) {
      pass_b<0,1,0><<<grid, blk, 0, stream>>>(nullptr, nullptr, ws0, ws0, thx, thz, l, 0);
      pass_a<0,1,0><<<grid, blk, 0, stream>>>(ws0, ws0, outre, thx, thz, l, 0);
    }
    pass_b<0,1,0><<<grid, blk, 0, stream>>>(nullptr, nullptr, ws0, ws0, thx, thz, 3, 0);
    pass_a<1,1,0><<<grid, blk, 0, stream>>>(ws0, nullptr, outre, thx, thz, 3, 0);
  }
}